// Round 2
// baseline (279.274 us; speedup 1.0000x reference)
//
#include <hip/hip_runtime.h>

// DigitCaps dynamic routing, B=512, N=4608, IN=16, OUT=32, CAPS=32.
// Identity: b-logits start at zero => softmax stays exactly uniform (1/32)
// across all 3 routing iterations (v is c-independent, so the agreement
// update is constant across c). Hence:
//   v[b,c,k] = squash_k((1/32) * sum_{n,j} x[b,n,j]*W[n,j,k])  for all c
// => one GEMM S[512,32] = X[512,73728] @ Wflat[73728,32], squash, broadcast.
//
// R2: latency-bound fix. Grid 512->2048 blocks (KSPLIT 64), RPW 2 (VGPR ~100
// -> 5 waves/SIMD), float4 x loads, transposed LDS wlds[c][k] with
// conflict-free ds_read_b128, split-K partials in d_ws (no atomics/zeroing).

#define NB 512
#define KTOT 73728          // N*IN
#define OUTC 32
#define NCAPS 32

#define KSPLIT 64
#define KCHUNK (KTOT / KSPLIT)   // 1152
#define KT 128                   // K-tile in LDS
#define NTILES (KCHUNK / KT)     // 9
#define NQ (KT / 4)              // 32 k-quads per tile
#define RPW 2                    // rows per lane (per half-wave)
#define NWAVES 4
#define RPB (NWAVES * 2 * RPW)   // 16 rows per block (2 halves/wave)
#define NRG (NB / RPB)           // 32 row-groups
#define KSTR (KT + 4)            // 132: padded k-stride per c-row (16B-aligned)

#define WS_NEED ((size_t)KSPLIT * NB * OUTC * 4)   // 4 MB of partials

__global__ __launch_bounds__(256) void zero_ws(float* __restrict__ S) {
    int i = blockIdx.x * 256 + threadIdx.x;
    if (i < NB * OUTC) S[i] = 0.0f;
}

template <bool PART>
__global__ __launch_bounds__(256) void gemm_k(
        const float* __restrict__ x, const float* __restrict__ w,
        float* __restrict__ S) {
    __shared__ float wlds[OUTC * KSTR];   // 32 x 132 floats = 16896 B
    const int t = threadIdx.x;
    const int lane = t & 63;
    const int l32 = lane & 31;
    const int half = lane >> 5;
    const int wave = t >> 6;
    const int bx = blockIdx.x, by = blockIdx.y;
    const int row0 = bx * RPB + wave * (2 * RPW) + half * RPW;
    const size_t kbase = (size_t)by * KCHUNK;

    // staging assignment: c = t&31, covers 8 k-quads per iter
    const int sc = t & 31;
    const int sh = t >> 5;                // 0..7

    float acc[RPW][OUTC];
#pragma unroll
    for (int r = 0; r < RPW; ++r)
#pragma unroll
        for (int c = 0; c < OUTC; ++c) acc[r][c] = 0.0f;

    const float4* xq[RPW];
#pragma unroll
    for (int r = 0; r < RPW; ++r)
        xq[r] = (const float4*)(x + (size_t)(row0 + r) * KTOT + kbase);

    for (int tile = 0; tile < NTILES; ++tile) {
        // ---- prefetch this tile's x quads (independent of LDS) ----
        float4 xv[RPW];
#pragma unroll
        for (int r = 0; r < RPW; ++r)
            xv[r] = xq[r][tile * NQ + l32];

        // ---- stage W-tile transposed into LDS: wlds[c][k] ----
        // global w is [k][c]; reads coalesced across the 32 c-lanes.
#pragma unroll
        for (int jj = 0; jj < 4; ++jj) {
            int kq = jj * 8 + sh;                 // quad 0..31 within tile
            int kk = 4 * kq;
            const float* wg = w + (kbase + (size_t)tile * KT + kk) * OUTC + sc;
            float w0 = wg[0];
            float w1 = wg[OUTC];
            float w2 = wg[2 * OUTC];
            float w3 = wg[3 * OUTC];
            *(float4*)&wlds[sc * KSTR + kk] = make_float4(w0, w1, w2, w3);
        }
        __syncthreads();

        // ---- compute: lane owns k-quad l32; both halves read same rows
        // (broadcast, conflict-free b128), FMA into 2 rows x 32 cols ----
#pragma unroll
        for (int c = 0; c < OUTC; ++c) {
            float4 wv = *(const float4*)&wlds[c * KSTR + 4 * l32];
#pragma unroll
            for (int r = 0; r < RPW; ++r) {
                float a = acc[r][c];
                a = fmaf(xv[r].x, wv.x, a);
                a = fmaf(xv[r].y, wv.y, a);
                a = fmaf(xv[r].z, wv.z, a);
                a = fmaf(xv[r].w, wv.w, a);
                acc[r][c] = a;
            }
        }
        __syncthreads();
    }

    // ---- reduce each acc over the 32 k-quad lanes of this half ----
#pragma unroll
    for (int r = 0; r < RPW; ++r) {
        float myv = 0.0f;
#pragma unroll
        for (int c = 0; c < OUTC; ++c) {
            float v = acc[r][c];
            v += __shfl_xor(v, 16, 64);
            v += __shfl_xor(v, 8, 64);
            v += __shfl_xor(v, 4, 64);
            v += __shfl_xor(v, 2, 64);
            v += __shfl_xor(v, 1, 64);
            if (l32 == c) myv = v;    // lane c of each half keeps column c
        }
        const int row = row0 + r;
        if (PART)
            S[((size_t)by * NB + row) * OUTC + l32] = myv;
        else
            atomicAdd(&S[(size_t)row * OUTC + l32], myv);
    }
}

template <bool PART>
__global__ __launch_bounds__(64) void finalize_k(const float* __restrict__ S,
                                                 float* __restrict__ out) {
    const int b = blockIdx.x;
    const int t = threadIdx.x;
    const int k = t & 31;
    const int h = t >> 5;
    float s;
    if (PART) {
        float a = 0.0f;
#pragma unroll
        for (int i = 0; i < KSPLIT / 2; ++i)
            a += S[((size_t)(h * (KSPLIT / 2) + i) * NB + b) * OUTC + k];
        a += __shfl_xor(a, 32, 64);   // combine the two halves
        s = a * (1.0f / 32.0f);
    } else {
        s = S[(size_t)b * OUTC + k] * (1.0f / 32.0f);
    }
    float sq = s * s;
    sq += __shfl_xor(sq, 16, 64);
    sq += __shfl_xor(sq, 8, 64);
    sq += __shfl_xor(sq, 4, 64);
    sq += __shfl_xor(sq, 2, 64);
    sq += __shfl_xor(sq, 1, 64);
    // squash: v = (sq/(1+sq)) * s / sqrt(sq)
    float scale = sq / ((1.0f + sq) * sqrtf(sq));
    float v = s * scale;
    float* orow = out + (size_t)b * (NCAPS * OUTC);
#pragma unroll
    for (int j = 0; j < 16; ++j)
        orow[(h + j * 2) * OUTC + k] = v;   // broadcast across capsules
}

extern "C" void kernel_launch(void* const* d_in, const int* in_sizes, int n_in,
                              void* d_out, int out_size, void* d_ws, size_t ws_size,
                              hipStream_t stream) {
    const float* x = (const float*)d_in[0];          // [512, 4608, 16] f32
    const float* w = (const float*)d_in[1];          // [4608, 16, 32] f32
    float* out = (float*)d_out;                      // [512, 32, 32] f32
    float* S = (float*)d_ws;

    if (ws_size >= WS_NEED) {
        // split-K partials: no zeroing, no atomics
        hipLaunchKernelGGL((gemm_k<true>), dim3(NRG, KSPLIT), dim3(256), 0, stream,
                           x, w, S);
        hipLaunchKernelGGL((finalize_k<true>), dim3(NB), dim3(64), 0, stream, S, out);
    } else {
        hipLaunchKernelGGL(zero_ws, dim3((NB * OUTC + 255) / 256), dim3(256), 0,
                           stream, S);
        hipLaunchKernelGGL((gemm_k<false>), dim3(NRG, KSPLIT), dim3(256), 0, stream,
                           x, w, S);
        hipLaunchKernelGGL((finalize_k<false>), dim3(NB), dim3(64), 0, stream, S, out);
    }
}

// Round 3
// 226.280 us; speedup vs baseline: 1.2342x; 1.2342x over previous
//
#include <hip/hip_runtime.h>

// DigitCaps dynamic routing, B=512, N=4608, IN=16, OUT=32, CAPS=32.
// Identity: b-logits start at zero => softmax stays exactly uniform (1/32)
// across all 3 routing iterations (v is c-independent, so the agreement
// update is constant across c). Hence:
//   v[b,c,k] = squash_k((1/32) * sum_{n,j} x[b,n,j]*W[n,j,k])  for all c
// => one GEMM S[512,32] = X[512,73728] @ Wflat[73728,32], squash, broadcast.
//
// R3: bf16 MFMA streaming GEMM. R2 was LDS-instr-throughput bound (~46 us
// structural floor) + barrier-drained. MFMA does the K-reduction in HW:
// no LDS, no __syncthreads, pure x-stream at HBM BW. W is pre-formatted
// into B-fragment order (wt_prep) so the hot loop is 4 loads + 2 MFMAs.

#define NB 512
#define KTOT 73728          // N*IN
#define OUTC 32
#define NCAPS 32

// ---- MFMA path constants ----
#define KSPLIT 128
#define KCHUNK (KTOT / KSPLIT)        // 576
#define NSTEP (KCHUNK / 32)           // 18 k-steps of 32
#define NSTEPS_TOT (KTOT / 32)        // 2304
#define WT_BYTES ((size_t)NSTEPS_TOT * 2 * 64 * 8 * 2)   // 4,718,592
#define SPA_BYTES ((size_t)KSPLIT * NB * OUTC * 4)       // 8,388,608
#define S_BYTES ((size_t)NB * OUTC * 4)                  // 65,536

typedef short bf16x8 __attribute__((ext_vector_type(8)));
typedef float f32x4 __attribute__((ext_vector_type(4)));

__device__ __forceinline__ unsigned int f2bf(float f) {
    union { float f; unsigned int u; } v; v.f = f;
    unsigned int u = v.u;
    return (u + 0x7fffu + ((u >> 16) & 1u)) >> 16;   // RNE to bf16 bits
}

// ---- W -> bf16 B-fragment layout ----
// Fragment for mfma_f32_16x16x32_bf16 B operand: lane holds
// B[k = kstep + (lane>>4)*8 + j][n = lane&15], j=0..7 contiguous.
// WT flat layout: [step 0..2303][chalf 0..1][lane 0..63][j 0..7] bf16.
__global__ __launch_bounds__(256) void wt_prep(const float* __restrict__ w,
                                               unsigned short* __restrict__ wt) {
    int tt = blockIdx.x * 256 + threadIdx.x;     // 0 .. 294911
    int lane = tt & 63;
    int h = (tt >> 6) & 1;
    int step = tt >> 7;
    int k0 = step * 32 + ((lane >> 4) & 3) * 8;
    int c = h * 16 + (lane & 15);
    const float* wp = w + (size_t)k0 * OUTC + c;
    unsigned int u[4];
#pragma unroll
    for (int j = 0; j < 4; ++j) {
        unsigned int lo = f2bf(wp[(2 * j) * OUTC]);
        unsigned int hi = f2bf(wp[(2 * j + 1) * OUTC]);
        u[j] = lo | (hi << 16);
    }
    *(uint4*)(wt + (size_t)tt * 8) = make_uint4(u[0], u[1], u[2], u[3]);
}

// ---- streaming MFMA GEMM, no LDS, no barriers ----
// wave = 16 rows x 32 cols; A-frag: A[m=lane&15][k=(lane>>4)*8+j] (verified
// layout); C/D: col=lane&15, row=(lane>>4)*4+reg (verified layout).
template <bool PART>
__global__ __launch_bounds__(256) void gemm_mfma(
        const float* __restrict__ x, const unsigned short* __restrict__ wt,
        float* __restrict__ S) {
    const int t = threadIdx.x;
    const int lane = t & 63;
    const int wave = t >> 6;
    const int bx = blockIdx.x;               // k-split index
    const int by = blockIdx.y;               // row-group (8)
    const int row0 = by * 64 + wave * 16;
    const int m = lane & 15;
    const int q = lane >> 4;
    const size_t kbase = (size_t)bx * KCHUNK;

    const float* xp = x + (size_t)(row0 + m) * KTOT + kbase + q * 8;
    const unsigned short* wp = wt + (kbase >> 5) * 1024 + lane * 8;

    f32x4 acc0 = {0.f, 0.f, 0.f, 0.f};
    f32x4 acc1 = {0.f, 0.f, 0.f, 0.f};

#pragma unroll 6
    for (int s = 0; s < NSTEP; ++s) {
        float4 xa = *(const float4*)xp;
        float4 xb = *(const float4*)(xp + 4);
        xp += 32;
        bf16x8 b0 = *(const bf16x8*)(wp);
        bf16x8 b1 = *(const bf16x8*)(wp + 512);
        wp += 1024;
        bf16x8 a;
        a[0] = (short)f2bf(xa.x); a[1] = (short)f2bf(xa.y);
        a[2] = (short)f2bf(xa.z); a[3] = (short)f2bf(xa.w);
        a[4] = (short)f2bf(xb.x); a[5] = (short)f2bf(xb.y);
        a[6] = (short)f2bf(xb.z); a[7] = (short)f2bf(xb.w);
        acc0 = __builtin_amdgcn_mfma_f32_16x16x32_bf16(a, b0, acc0, 0, 0, 0);
        acc1 = __builtin_amdgcn_mfma_f32_16x16x32_bf16(a, b1, acc1, 0, 0, 0);
    }

    // epilogue: C/D col = m, row_local = q*4 + reg
#pragma unroll
    for (int r = 0; r < 4; ++r) {
        const int row = row0 + q * 4 + r;
        if (PART) {
            float* dst = S + ((size_t)bx * NB + row) * OUTC;
            dst[m] = acc0[r];
            dst[16 + m] = acc1[r];
        } else {
            atomicAdd(&S[(size_t)row * OUTC + m], acc0[r]);
            atomicAdd(&S[(size_t)row * OUTC + 16 + m], acc1[r]);
        }
    }
}

__global__ __launch_bounds__(256) void zero_s(float* __restrict__ S) {
    int i = blockIdx.x * 256 + threadIdx.x;
    if (i < NB * OUTC) S[i] = 0.0f;
}

// finalize: sum split-K partials (if PART), scale 1/32, squash, broadcast.
template <bool PART>
__global__ __launch_bounds__(64) void finalize_k(const float* __restrict__ S,
                                                 float* __restrict__ out) {
    const int b = blockIdx.x;
    const int t = threadIdx.x;
    const int k = t & 31;
    const int h = t >> 5;
    float s;
    if (PART) {
        float a = 0.0f;
#pragma unroll 8
        for (int i = 0; i < KSPLIT / 2; ++i)
            a += S[((size_t)(h * (KSPLIT / 2) + i) * NB + b) * OUTC + k];
        a += __shfl_xor(a, 32, 64);     // combine the two halves
        s = a * (1.0f / 32.0f);
    } else {
        s = S[(size_t)b * OUTC + k] * (1.0f / 32.0f);
    }
    float sq = s * s;
    sq += __shfl_xor(sq, 16, 64);
    sq += __shfl_xor(sq, 8, 64);
    sq += __shfl_xor(sq, 4, 64);
    sq += __shfl_xor(sq, 2, 64);
    sq += __shfl_xor(sq, 1, 64);
    float scale = sq / ((1.0f + sq) * sqrtf(sq));   // squash
    float v = s * scale;
    float* orow = out + (size_t)b * (NCAPS * OUTC);
#pragma unroll
    for (int j = 0; j < 16; ++j)
        orow[(h + j * 2) * OUTC + k] = v;           // broadcast across capsules
}

// ---------- tier C fallback (proven R1/R2-style fp32 LDS kernel) ----------
#define FKSPLIT 64
#define FKCHUNK 1152
#define FKT 128
#define FNQ 32
#define FRPW 2
#define FKSTR 132

__global__ __launch_bounds__(256) void gemm_fb(
        const float* __restrict__ x, const float* __restrict__ w,
        float* __restrict__ S) {
    __shared__ float wlds[OUTC * FKSTR];
    const int t = threadIdx.x;
    const int lane = t & 63;
    const int l32 = lane & 31;
    const int half = lane >> 5;
    const int wave = t >> 6;
    const int row0 = blockIdx.x * 16 + wave * 4 + half * FRPW;
    const size_t kbase = (size_t)blockIdx.y * FKCHUNK;
    const int sc = t & 31;
    const int sh = t >> 5;

    float acc[FRPW][OUTC];
#pragma unroll
    for (int r = 0; r < FRPW; ++r)
#pragma unroll
        for (int c = 0; c < OUTC; ++c) acc[r][c] = 0.0f;

    const float4* xq[FRPW];
#pragma unroll
    for (int r = 0; r < FRPW; ++r)
        xq[r] = (const float4*)(x + (size_t)(row0 + r) * KTOT + kbase);

    for (int tile = 0; tile < FKCHUNK / FKT; ++tile) {
        float4 xv[FRPW];
#pragma unroll
        for (int r = 0; r < FRPW; ++r)
            xv[r] = xq[r][tile * FNQ + l32];
#pragma unroll
        for (int jj = 0; jj < 4; ++jj) {
            int kk = 4 * (jj * 8 + sh);
            const float* wg = w + (kbase + (size_t)tile * FKT + kk) * OUTC + sc;
            *(float4*)&wlds[sc * FKSTR + kk] =
                make_float4(wg[0], wg[OUTC], wg[2 * OUTC], wg[3 * OUTC]);
        }
        __syncthreads();
#pragma unroll
        for (int c = 0; c < OUTC; ++c) {
            float4 wv = *(const float4*)&wlds[c * FKSTR + 4 * l32];
#pragma unroll
            for (int r = 0; r < FRPW; ++r) {
                float a = acc[r][c];
                a = fmaf(xv[r].x, wv.x, a);
                a = fmaf(xv[r].y, wv.y, a);
                a = fmaf(xv[r].z, wv.z, a);
                a = fmaf(xv[r].w, wv.w, a);
                acc[r][c] = a;
            }
        }
        __syncthreads();
    }
#pragma unroll
    for (int r = 0; r < FRPW; ++r) {
        float myv = 0.0f;
#pragma unroll
        for (int c = 0; c < OUTC; ++c) {
            float v = acc[r][c];
            v += __shfl_xor(v, 16, 64);
            v += __shfl_xor(v, 8, 64);
            v += __shfl_xor(v, 4, 64);
            v += __shfl_xor(v, 2, 64);
            v += __shfl_xor(v, 1, 64);
            if (l32 == c) myv = v;
        }
        atomicAdd(&S[(size_t)(row0 + r) * OUTC + l32], myv);
    }
}
// --------------------------------------------------------------------------

extern "C" void kernel_launch(void* const* d_in, const int* in_sizes, int n_in,
                              void* d_out, int out_size, void* d_ws, size_t ws_size,
                              hipStream_t stream) {
    const float* x = (const float*)d_in[0];          // [512, 4608, 16] f32
    const float* w = (const float*)d_in[1];          // [4608, 16, 32] f32
    float* out = (float*)d_out;                      // [512, 32, 32] f32

    if (ws_size >= WT_BYTES + SPA_BYTES) {
        // Tier A: MFMA + split-K partials (no atomics, no zeroing)
        unsigned short* wt = (unsigned short*)d_ws;
        float* S = (float*)((char*)d_ws + WT_BYTES);
        hipLaunchKernelGGL(wt_prep, dim3(NSTEPS_TOT * 128 / 256), dim3(256), 0,
                           stream, w, wt);
        hipLaunchKernelGGL((gemm_mfma<true>), dim3(KSPLIT, 8), dim3(256), 0,
                           stream, x, wt, S);
        hipLaunchKernelGGL((finalize_k<true>), dim3(NB), dim3(64), 0, stream,
                           S, out);
    } else if (ws_size >= WT_BYTES + S_BYTES) {
        // Tier B: MFMA + atomic accumulation
        unsigned short* wt = (unsigned short*)d_ws;
        float* S = (float*)((char*)d_ws + WT_BYTES);
        hipLaunchKernelGGL(wt_prep, dim3(NSTEPS_TOT * 128 / 256), dim3(256), 0,
                           stream, w, wt);
        hipLaunchKernelGGL(zero_s, dim3((NB * OUTC + 255) / 256), dim3(256), 0,
                           stream, S);
        hipLaunchKernelGGL((gemm_mfma<false>), dim3(KSPLIT, 8), dim3(256), 0,
                           stream, x, wt, S);
        hipLaunchKernelGGL((finalize_k<false>), dim3(NB), dim3(64), 0, stream,
                           S, out);
    } else {
        // Tier C: proven fp32 LDS fallback (needs only 64 KB)
        float* S = (float*)d_ws;
        hipLaunchKernelGGL(zero_s, dim3((NB * OUTC + 255) / 256), dim3(256), 0,
                           stream, S);
        hipLaunchKernelGGL(gemm_fb, dim3(32, FKSPLIT), dim3(256), 0, stream,
                           x, w, S);
        hipLaunchKernelGGL((finalize_k<false>), dim3(NB), dim3(64), 0, stream,
                           S, out);
    }
}